// Round 3
// baseline (622.647 us; speedup 1.0000x reference)
//
#include <hip/hip_runtime.h>
#include <math.h>

// Problem constants (fixed by the reference): B=8, C=D=512, H=W=128
#define BB   8
#define CC   512
#define DD   512
#define HW   16384
#define HW4  4096    // HW / 4 (float4 count per (b,c) row)
#define NCH  512     // chunks per batch; chunk = 32 positions = 8 float4

// Algebraic restructuring (query length == 1):
//   logits = (q@Wk)·x  (+ q·bk, dropped: softmax shift-invariant)
//   gate   = Wv·(attn-pooled x) + bv   (since sum(attn)==1)
// SINGLE-SWEEP attention: k_fused stages x[b, :, 32-pos chunk] in REGISTERS,
// computes chunk logits, chunk-local softmax (p = exp(l-M), stats), and the
// chunk's pooled partial part[c] = sum_pos p*x — all from the same registers.
// x is read ONCE here + once in k_out: 0.82 GB total vs 1.07 GB before.
// Lesson history: r1 fused-pool re-READ x (no win, latency chains); registers
// are the only place the second use is free.

// ---- A: qk[b,c] = sum_o (ctx[b]·Wq[o] + bq[o]) * Wk[o,c]  (fused, tiny) ----
__global__ __launch_bounds__(256) void k_qk2(const float* __restrict__ ctx,
                                             const float* __restrict__ Wq,
                                             const float* __restrict__ bq,
                                             const float* __restrict__ Wk,
                                             float* __restrict__ qk) {
    __shared__ float qs[CC];
    int b    = blockIdx.x >> 1;
    int half = blockIdx.x & 1;
    const float4* cr = (const float4*)(ctx + (size_t)b * DD);
    for (int c = threadIdx.x; c < CC; c += 256) {
        const float4* wr = (const float4*)(Wq + (size_t)c * DD);
        float acc = 0.f;
        #pragma unroll 8
        for (int d = 0; d < DD / 4; ++d) {
            float4 a = cr[d], w = wr[d];
            acc += a.x * w.x + a.y * w.y + a.z * w.z + a.w * w.w;
        }
        qs[c] = acc + bq[c];
    }
    __syncthreads();
    int c = half * 256 + threadIdx.x;
    float acc = 0.f;
    #pragma unroll 8
    for (int o = 0; o < CC; ++o) acc += qs[o] * Wk[(size_t)o * CC + c];
    qk[b * CC + c] = acc;
}

// ---- B: single-sweep logits + chunk softmax + pooled partials ----
// Block = (b, chunk of 32 positions), 512 threads (8 waves).
// Thread (w, l): lg = l>>3 channel subgroup, lp = l&7 position-float4.
// Stages x[c = 64w+8it+lg, pos4 = lp] for it=0..7 (8 float4 = 32 VGPR).
__global__ __launch_bounds__(512, 4) void k_fused(const float* __restrict__ x,
                                                  const float* __restrict__ qk,
                                                  float* __restrict__ part,    // [BB*NCH][CC]
                                                  float* __restrict__ stats) { // [BB*NCH][2]
    __shared__ float qs[CC];
    __shared__ float4 comb[7][8];
    __shared__ float4 p4s[8];
    __shared__ __align__(16) float partLDS[CC];
    int b   = blockIdx.x >> 9;                    // NCH = 512 chunks per batch
    int cid = blockIdx.x & (NCH - 1);
    int tid = threadIdx.x;
    int w = tid >> 6, l = tid & 63;
    int lg = l >> 3, lp = l & 7;
    for (int i = tid; i < CC; i += 512) qs[i] = qk[b * CC + i];
    __syncthreads();
    const float4* x4 = (const float4*)x;
    size_t base = ((size_t)(b * CC + 64 * w + lg)) * HW4 + cid * 8 + lp;
    float4 xr[8];
    #pragma unroll
    for (int it = 0; it < 8; ++it) xr[it] = x4[base + (size_t)it * 8 * HW4];
    // Phase 1: chunk logits. In-thread over 8 channels, then xor over lg bits.
    float4 la = { 0.f, 0.f, 0.f, 0.f };
    #pragma unroll
    for (int it = 0; it < 8; ++it) {
        float qv = qs[64 * w + 8 * it + lg];
        la.x += qv * xr[it].x; la.y += qv * xr[it].y;
        la.z += qv * xr[it].z; la.w += qv * xr[it].w;
    }
    #pragma unroll
    for (int st = 8; st <= 32; st <<= 1) {
        la.x += __shfl_xor(la.x, st); la.y += __shfl_xor(la.y, st);
        la.z += __shfl_xor(la.z, st); la.w += __shfl_xor(la.w, st);
    }
    if (w > 0 && l < 8) comb[w - 1][l] = la;
    __syncthreads();
    // Phase 2: wave 0 lanes 0..7 finish logits, chunk-local softmax over 32.
    if (w == 0 && l < 8) {
        #pragma unroll
        for (int i = 0; i < 7; ++i) {
            float4 t = comb[i][l];
            la.x += t.x; la.y += t.y; la.z += t.z; la.w += t.w;
        }
        const float scale = 0.04419417382415922f; // 512^-0.5
        la.x *= scale; la.y *= scale; la.z *= scale; la.w *= scale;
        float m = fmaxf(fmaxf(la.x, la.y), fmaxf(la.z, la.w));
        m = fmaxf(m, __shfl_xor(m, 1));
        m = fmaxf(m, __shfl_xor(m, 2));
        m = fmaxf(m, __shfl_xor(m, 4));
        float4 p;
        p.x = expf(la.x - m); p.y = expf(la.y - m);
        p.z = expf(la.z - m); p.w = expf(la.w - m);
        float s = p.x + p.y + p.z + p.w;
        s += __shfl_xor(s, 1); s += __shfl_xor(s, 2); s += __shfl_xor(s, 4);
        p4s[l] = p;
        if (l == 0) { stats[blockIdx.x * 2] = m; stats[blockIdx.x * 2 + 1] = s; }
    }
    __syncthreads();
    // Phase 3: pooled partials from REGISTERS. xor over lp bits (8 indep chains).
    float4 pw = p4s[lp];
    #pragma unroll
    for (int it = 0; it < 8; ++it) {
        float r = pw.x * xr[it].x + pw.y * xr[it].y + pw.z * xr[it].z + pw.w * xr[it].w;
        r += __shfl_xor(r, 1); r += __shfl_xor(r, 2); r += __shfl_xor(r, 4);
        if (lp == 0) partLDS[64 * w + 8 * it + lg] = r;
    }
    __syncthreads();
    if (tid < CC / 4)
        ((float4*)(part + (size_t)blockIdx.x * CC))[tid] = ((float4*)partLDS)[tid];
}

// ---- C: merge chunks -> pooled[b,c]  (reads 8 MB part, tiny) ----
// pooled[c] = sum_ch wgt[ch]*part[ch][c], wgt[ch] = e^{M_ch-M}/D.
__global__ __launch_bounds__(256) void k_combine(const float* __restrict__ part,
                                                 const float* __restrict__ stats,
                                                 float* __restrict__ pooled) {
    __shared__ float wgt[NCH];
    __shared__ float redm[4], reds[4];
    int b = blockIdx.x >> 1, half = blockIdx.x & 1;
    int tid = threadIdx.x;
    float m1 = stats[((size_t)b * NCH + tid) * 2];
    float s1 = stats[((size_t)b * NCH + tid) * 2 + 1];
    float m2 = stats[((size_t)b * NCH + tid + 256) * 2];
    float s2 = stats[((size_t)b * NCH + tid + 256) * 2 + 1];
    float m = fmaxf(m1, m2);
    #pragma unroll
    for (int off = 32; off; off >>= 1) m = fmaxf(m, __shfl_xor(m, off));
    if ((tid & 63) == 0) redm[tid >> 6] = m;
    __syncthreads();
    m = fmaxf(fmaxf(redm[0], redm[1]), fmaxf(redm[2], redm[3]));
    float w1 = expf(m1 - m), w2 = expf(m2 - m);
    float d = w1 * s1 + w2 * s2;
    #pragma unroll
    for (int off = 32; off; off >>= 1) d += __shfl_xor(d, off);
    if ((tid & 63) == 0) reds[tid >> 6] = d;
    __syncthreads();
    float inv = 1.f / (reds[0] + reds[1] + reds[2] + reds[3]);
    wgt[tid] = w1 * inv; wgt[tid + 256] = w2 * inv;
    __syncthreads();
    int c = half * 256 + tid;
    float acc = 0.f;
    #pragma unroll 8
    for (int ch = 0; ch < NCH; ++ch)
        acc += wgt[ch] * part[((size_t)b * NCH + ch) * CC + c];
    pooled[b * CC + c] = acc;
}

// ---- D: gate[b,o] = Wv[o,:]·pooled[b,:] + bv[o]   (tiny) ----
__global__ __launch_bounds__(256) void k_gate(const float* __restrict__ pooled,
                                              const float* __restrict__ Wv,
                                              const float* __restrict__ bv,
                                              float* __restrict__ gate) {
    int t = blockIdx.x * 256 + threadIdx.x;       // 0..4095
    int b = t >> 9, o = t & (CC - 1);
    const float4* pr = (const float4*)(pooled + (size_t)b * CC);
    const float4* wr = (const float4*)(Wv + (size_t)o * CC);
    float acc = 0.f;
    #pragma unroll 8
    for (int i = 0; i < CC / 4; ++i) {
        float4 pv = pr[i], w = wr[i];
        acc += pv.x * w.x + pv.y * w.y + pv.z * w.z + pv.w * w.w;
    }
    gate[t] = acc + bv[o];
}

// ---- E: out[b,c,hw] = x[b,c,hw] * gate[b,c]   (read+write: 536 MB) ----
__global__ __launch_bounds__(256) void k_out(const float* __restrict__ x,
                                             const float* __restrict__ gate,
                                             float* __restrict__ out) {
    int bc = blockIdx.x;                          // 0..4095
    float g = gate[bc];
    const float4* xr = (const float4*)x   + (size_t)bc * HW4;
    float4*       orow = (float4*)out     + (size_t)bc * HW4;
    #pragma unroll 8
    for (int i = threadIdx.x; i < HW4; i += 256) {
        float4 v = xr[i];
        float4 o = { v.x * g, v.y * g, v.z * g, v.w * g };
        orow[i] = o;
    }
}

extern "C" void kernel_launch(void* const* d_in, const int* in_sizes, int n_in,
                              void* d_out, int out_size, void* d_ws, size_t ws_size,
                              hipStream_t stream) {
    const float* x   = (const float*)d_in[0];
    const float* ctx = (const float*)d_in[1];
    const float* Wq  = (const float*)d_in[2];
    const float* bq  = (const float*)d_in[3];
    const float* Wk  = (const float*)d_in[4];
    // d_in[5] = bk: per-batch constant in logits -> dropped (softmax shift-invariant)
    const float* Wv  = (const float*)d_in[6];
    const float* bv  = (const float*)d_in[7];
    float* out = (float*)d_out;

    // Workspace layout (floats): everything written before read, no zero-init.
    float* ws     = (float*)d_ws;
    float* qk     = ws;                 // 4096
    float* pooled = ws + 4096;          // 4096
    float* gate   = ws + 8192;          // 4096
    float* stats  = ws + 12288;         // 8192  (4096 chunks x {M, s})
    float* part   = ws + 20480;         // 2 M floats (4096 chunks x 512 channels)

    k_qk2    <<<  16, 256, 0, stream>>>(ctx, Wq, bq, Wk, qk);
    k_fused  <<<4096, 512, 0, stream>>>(x, qk, part, stats);
    k_combine<<<  16, 256, 0, stream>>>(part, stats, pooled);
    k_gate   <<<  16, 256, 0, stream>>>(pooled, Wv, bv, gate);
    k_out    <<<4096, 256, 0, stream>>>(x, gate, out);
}

// Round 5
// 604.266 us; speedup vs baseline: 1.0304x; 1.0304x over previous
//
#include <hip/hip_runtime.h>
#include <math.h>

// Problem constants (fixed by the reference): B=8, C=D=512, H=W=128
#define BB   8
#define CC   512
#define DD   512
#define HW   16384
#define HW4  4096    // HW / 4 (float4 count per (b,c) row)
#define NCH  512     // chunks per batch; chunk = 32 positions = 8 float4

typedef float f32x4 __attribute__((ext_vector_type(4)));  // NT-store-compatible

// Algebraic restructuring (query length == 1):
//   logits = (q@Wk)·x  (+ q·bk, dropped: softmax shift-invariant)
//   gate   = Wv·(attn-pooled x) + bv   (since sum(attn)==1)
// SINGLE-SWEEP attention: k_fused stages x[b, :, 32-pos chunk] in REGISTERS,
// computes chunk logits, chunk-local softmax (p = exp(l-M), stats), and the
// chunk's pooled partial part[c] = sum_pos p*x — all from the same registers.
// x is read ONCE here + once in k_out.
// Evidence trail (R0-R3): dur is insensitive to traffic (±1% across 3-pass,
// 2.5-pass, 2-pass structures) -> timed region carries ~250-300 µs of harness
// poison fills (10 fills/iter, ws fill = 1 GiB/165 µs). This round: squeeze
// the controllable part (NT stores in k_out, combine+gate merged, 4 launches).

// ---- A: qk[b,c] = sum_o (ctx[b]·Wq[o] + bq[o]) * Wk[o,c]  (fused, tiny) ----
__global__ __launch_bounds__(256) void k_qk2(const float* __restrict__ ctx,
                                             const float* __restrict__ Wq,
                                             const float* __restrict__ bq,
                                             const float* __restrict__ Wk,
                                             float* __restrict__ qk) {
    __shared__ float qs[CC];
    int b    = blockIdx.x >> 1;
    int half = blockIdx.x & 1;
    const float4* cr = (const float4*)(ctx + (size_t)b * DD);
    for (int c = threadIdx.x; c < CC; c += 256) {
        const float4* wr = (const float4*)(Wq + (size_t)c * DD);
        float acc = 0.f;
        #pragma unroll 8
        for (int d = 0; d < DD / 4; ++d) {
            float4 a = cr[d], w = wr[d];
            acc += a.x * w.x + a.y * w.y + a.z * w.z + a.w * w.w;
        }
        qs[c] = acc + bq[c];
    }
    __syncthreads();
    int c = half * 256 + threadIdx.x;
    float acc = 0.f;
    #pragma unroll 8
    for (int o = 0; o < CC; ++o) acc += qs[o] * Wk[(size_t)o * CC + c];
    qk[b * CC + c] = acc;
}

// ---- B: single-sweep logits + chunk softmax + pooled partials ----
// Block = (b, chunk of 32 positions), 512 threads (8 waves).
// Thread (w, l): lg = l>>3 channel subgroup, lp = l&7 position-float4.
// Stages x[c = 64w+8it+lg, pos4 = lp] for it=0..7 (8 float4 = 32 VGPR).
__global__ __launch_bounds__(512, 4) void k_fused(const float* __restrict__ x,
                                                  const float* __restrict__ qk,
                                                  float* __restrict__ part,    // [BB*NCH][CC]
                                                  float* __restrict__ stats) { // [BB*NCH][2]
    __shared__ float qs[CC];
    __shared__ float4 comb[7][8];
    __shared__ float4 p4s[8];
    __shared__ __align__(16) float partLDS[CC];
    int b   = blockIdx.x >> 9;                    // NCH = 512 chunks per batch
    int cid = blockIdx.x & (NCH - 1);
    int tid = threadIdx.x;
    int w = tid >> 6, l = tid & 63;
    int lg = l >> 3, lp = l & 7;
    for (int i = tid; i < CC; i += 512) qs[i] = qk[b * CC + i];
    __syncthreads();
    const float4* x4 = (const float4*)x;
    size_t base = ((size_t)(b * CC + 64 * w + lg)) * HW4 + cid * 8 + lp;
    float4 xr[8];
    #pragma unroll
    for (int it = 0; it < 8; ++it) xr[it] = x4[base + (size_t)it * 8 * HW4];
    // Phase 1: chunk logits. In-thread over 8 channels, then xor over lg bits.
    float4 la = { 0.f, 0.f, 0.f, 0.f };
    #pragma unroll
    for (int it = 0; it < 8; ++it) {
        float qv = qs[64 * w + 8 * it + lg];
        la.x += qv * xr[it].x; la.y += qv * xr[it].y;
        la.z += qv * xr[it].z; la.w += qv * xr[it].w;
    }
    #pragma unroll
    for (int st = 8; st <= 32; st <<= 1) {
        la.x += __shfl_xor(la.x, st); la.y += __shfl_xor(la.y, st);
        la.z += __shfl_xor(la.z, st); la.w += __shfl_xor(la.w, st);
    }
    if (w > 0 && l < 8) comb[w - 1][l] = la;
    __syncthreads();
    // Phase 2: wave 0 lanes 0..7 finish logits, chunk-local softmax over 32.
    if (w == 0 && l < 8) {
        #pragma unroll
        for (int i = 0; i < 7; ++i) {
            float4 t = comb[i][l];
            la.x += t.x; la.y += t.y; la.z += t.z; la.w += t.w;
        }
        const float scale = 0.04419417382415922f; // 512^-0.5
        la.x *= scale; la.y *= scale; la.z *= scale; la.w *= scale;
        float m = fmaxf(fmaxf(la.x, la.y), fmaxf(la.z, la.w));
        m = fmaxf(m, __shfl_xor(m, 1));
        m = fmaxf(m, __shfl_xor(m, 2));
        m = fmaxf(m, __shfl_xor(m, 4));
        float4 p;
        p.x = expf(la.x - m); p.y = expf(la.y - m);
        p.z = expf(la.z - m); p.w = expf(la.w - m);
        float s = p.x + p.y + p.z + p.w;
        s += __shfl_xor(s, 1); s += __shfl_xor(s, 2); s += __shfl_xor(s, 4);
        p4s[l] = p;
        if (l == 0) { stats[blockIdx.x * 2] = m; stats[blockIdx.x * 2 + 1] = s; }
    }
    __syncthreads();
    // Phase 3: pooled partials from REGISTERS. xor over lp bits (8 indep chains).
    float4 pw = p4s[lp];
    #pragma unroll
    for (int it = 0; it < 8; ++it) {
        float r = pw.x * xr[it].x + pw.y * xr[it].y + pw.z * xr[it].z + pw.w * xr[it].w;
        r += __shfl_xor(r, 1); r += __shfl_xor(r, 2); r += __shfl_xor(r, 4);
        if (lp == 0) partLDS[64 * w + 8 * it + lg] = r;
    }
    __syncthreads();
    if (tid < CC / 4)
        ((float4*)(part + (size_t)blockIdx.x * CC))[tid] = ((float4*)partLDS)[tid];
}

// ---- C: merged combine+gate (one 16-block kernel, pooled stays in LDS) ----
// pooled[c] = sum_ch wgt[ch]*part[ch][c], wgt[ch] = e^{M_ch-M}/D, then
// gate[b,o] = Wv[o,:]·pooled + bv[o] for this block's half of o.
__global__ __launch_bounds__(256) void k_cg(const float* __restrict__ part,
                                            const float* __restrict__ stats,
                                            const float* __restrict__ Wv,
                                            const float* __restrict__ bv,
                                            float* __restrict__ gate) {
    __shared__ float wgt[NCH];
    __shared__ __align__(16) float pooledLDS[CC];
    __shared__ float redm[4], reds[4];
    int b = blockIdx.x >> 1, half = blockIdx.x & 1;
    int tid = threadIdx.x;
    float m1 = stats[((size_t)b * NCH + tid) * 2];
    float s1 = stats[((size_t)b * NCH + tid) * 2 + 1];
    float m2 = stats[((size_t)b * NCH + tid + 256) * 2];
    float s2 = stats[((size_t)b * NCH + tid + 256) * 2 + 1];
    float m = fmaxf(m1, m2);
    #pragma unroll
    for (int off = 32; off; off >>= 1) m = fmaxf(m, __shfl_xor(m, off));
    if ((tid & 63) == 0) redm[tid >> 6] = m;
    __syncthreads();
    m = fmaxf(fmaxf(redm[0], redm[1]), fmaxf(redm[2], redm[3]));
    float w1 = expf(m1 - m), w2 = expf(m2 - m);
    float d = w1 * s1 + w2 * s2;
    #pragma unroll
    for (int off = 32; off; off >>= 1) d += __shfl_xor(d, off);
    if ((tid & 63) == 0) reds[tid >> 6] = d;
    __syncthreads();
    float inv = 1.f / (reds[0] + reds[1] + reds[2] + reds[3]);
    wgt[tid] = w1 * inv; wgt[tid + 256] = w2 * inv;
    __syncthreads();
    // pooled (full 512 channels per block; redundant x2 per batch, trivial)
    float acc0 = 0.f, acc1 = 0.f;
    #pragma unroll 8
    for (int ch = 0; ch < NCH; ++ch) {
        const float* pr = part + ((size_t)b * NCH + ch) * CC;
        float w = wgt[ch];
        acc0 += w * pr[tid];
        acc1 += w * pr[tid + 256];
    }
    pooledLDS[tid] = acc0; pooledLDS[tid + 256] = acc1;
    __syncthreads();
    int o = half * 256 + tid;
    const float4* wr = (const float4*)(Wv + (size_t)o * CC);
    const float4* pl = (const float4*)pooledLDS;   // wave-uniform idx -> broadcast
    float acc = 0.f;
    #pragma unroll 8
    for (int i = 0; i < CC / 4; ++i) {
        float4 w = wr[i], p = pl[i];
        acc += w.x * p.x + w.y * p.y + w.z * p.z + w.w * p.w;
    }
    gate[b * CC + o] = acc + bv[o];
}

// ---- D: out[b,c,hw] = x[b,c,hw] * gate[b,c]   (read+write: 536 MB) ----
// NT stores (via clang ext_vector type — HIP float4 is rejected by the
// builtin): out is write-once/never-read -> skip cache allocation, keep
// L2/L3 for x, more effective write BW on the mixed stream.
__global__ __launch_bounds__(256) void k_out(const float* __restrict__ x,
                                             const float* __restrict__ gate,
                                             float* __restrict__ out) {
    int bc = blockIdx.x;                          // 0..4095
    float g = gate[bc];
    const float4* xr   = (const float4*)x + (size_t)bc * HW4;
    f32x4*       orow  = (f32x4*)out      + (size_t)bc * HW4;
    #pragma unroll 8
    for (int i = threadIdx.x; i < HW4; i += 256) {
        float4 v = xr[i];
        f32x4 o = { v.x * g, v.y * g, v.z * g, v.w * g };
        __builtin_nontemporal_store(o, orow + i);
    }
}

extern "C" void kernel_launch(void* const* d_in, const int* in_sizes, int n_in,
                              void* d_out, int out_size, void* d_ws, size_t ws_size,
                              hipStream_t stream) {
    const float* x   = (const float*)d_in[0];
    const float* ctx = (const float*)d_in[1];
    const float* Wq  = (const float*)d_in[2];
    const float* bq  = (const float*)d_in[3];
    const float* Wk  = (const float*)d_in[4];
    // d_in[5] = bk: per-batch constant in logits -> dropped (softmax shift-invariant)
    const float* Wv  = (const float*)d_in[6];
    const float* bv  = (const float*)d_in[7];
    float* out = (float*)d_out;

    // Workspace layout (floats): everything written before read, no zero-init.
    float* ws    = (float*)d_ws;
    float* qk    = ws;                  // 4096
    float* gate  = ws + 4096;           // 4096
    float* stats = ws + 8192;           // 8192  (4096 chunks x {M, s})
    float* part  = ws + 16384;          // 2 M floats (4096 chunks x 512 channels)

    k_qk2  <<<  16, 256, 0, stream>>>(ctx, Wq, bq, Wk, qk);
    k_fused<<<4096, 512, 0, stream>>>(x, qk, part, stats);
    k_cg   <<<  16, 256, 0, stream>>>(part, stats, Wv, bv, gate);
    k_out  <<<4096, 256, 0, stream>>>(x, gate, out);
}

// Round 6
// 602.828 us; speedup vs baseline: 1.0329x; 1.0024x over previous
//
#include <hip/hip_runtime.h>
#include <math.h>

// Problem constants (fixed by the reference): B=8, C=D=512, H=W=128
#define BB   8
#define CC   512
#define DD   512
#define HW   16384
#define HW4  4096    // HW / 4 (float4 count per (b,c) row)
#define NCH  512     // chunks per batch; chunk = 32 positions = 8 float4

typedef float f32x4 __attribute__((ext_vector_type(4)));  // NT-builtin-compatible

// Algebraic restructuring (query length == 1):
//   logits = (q@Wk)·x  (+ q·bk, dropped: softmax shift-invariant)
//   gate   = Wv·(attn-pooled x) + bv   (since sum(attn)==1)
// SINGLE-SWEEP attention: k_fused stages x[b, :, 32-pos chunk] in REGISTERS,
// computes chunk logits, chunk-local softmax (p = exp(l-M), stats), and the
// chunk's pooled partial part[c] = sum_pos p*x — all from the same registers.
// x is read ONCE here + once in k_out.
// Evidence trail (R0-R5): dur is insensitive to traffic/structure (±1% over
// five pipelines); only cache-path control moved it (NT stores: -15 µs).
// Timed region carries ~245 µs of harness poison fills (ws fill 1 GiB/163 µs
// observed) — untouchable. This round: NT LOADS in k_out (x is read-last-time,
// zero reuse to protect; skip L2/L3 allocation on 268 MB of dead lines).

// ---- A: qk[b,c] = sum_o (ctx[b]·Wq[o] + bq[o]) * Wk[o,c]  (fused, tiny) ----
__global__ __launch_bounds__(256) void k_qk2(const float* __restrict__ ctx,
                                             const float* __restrict__ Wq,
                                             const float* __restrict__ bq,
                                             const float* __restrict__ Wk,
                                             float* __restrict__ qk) {
    __shared__ float qs[CC];
    int b    = blockIdx.x >> 1;
    int half = blockIdx.x & 1;
    const float4* cr = (const float4*)(ctx + (size_t)b * DD);
    for (int c = threadIdx.x; c < CC; c += 256) {
        const float4* wr = (const float4*)(Wq + (size_t)c * DD);
        float acc = 0.f;
        #pragma unroll 8
        for (int d = 0; d < DD / 4; ++d) {
            float4 a = cr[d], w = wr[d];
            acc += a.x * w.x + a.y * w.y + a.z * w.z + a.w * w.w;
        }
        qs[c] = acc + bq[c];
    }
    __syncthreads();
    int c = half * 256 + threadIdx.x;
    float acc = 0.f;
    #pragma unroll 8
    for (int o = 0; o < CC; ++o) acc += qs[o] * Wk[(size_t)o * CC + c];
    qk[b * CC + c] = acc;
}

// ---- B: single-sweep logits + chunk softmax + pooled partials ----
// Block = (b, chunk of 32 positions), 512 threads (8 waves).
// Thread (w, l): lg = l>>3 channel subgroup, lp = l&7 position-float4.
// Stages x[c = 64w+8it+lg, pos4 = lp] for it=0..7 (8 float4 = 32 VGPR).
__global__ __launch_bounds__(512, 4) void k_fused(const float* __restrict__ x,
                                                  const float* __restrict__ qk,
                                                  float* __restrict__ part,    // [BB*NCH][CC]
                                                  float* __restrict__ stats) { // [BB*NCH][2]
    __shared__ float qs[CC];
    __shared__ float4 comb[7][8];
    __shared__ float4 p4s[8];
    __shared__ __align__(16) float partLDS[CC];
    int b   = blockIdx.x >> 9;                    // NCH = 512 chunks per batch
    int cid = blockIdx.x & (NCH - 1);
    int tid = threadIdx.x;
    int w = tid >> 6, l = tid & 63;
    int lg = l >> 3, lp = l & 7;
    for (int i = tid; i < CC; i += 512) qs[i] = qk[b * CC + i];
    __syncthreads();
    const float4* x4 = (const float4*)x;
    size_t base = ((size_t)(b * CC + 64 * w + lg)) * HW4 + cid * 8 + lp;
    float4 xr[8];
    #pragma unroll
    for (int it = 0; it < 8; ++it) xr[it] = x4[base + (size_t)it * 8 * HW4];
    // Phase 1: chunk logits. In-thread over 8 channels, then xor over lg bits.
    float4 la = { 0.f, 0.f, 0.f, 0.f };
    #pragma unroll
    for (int it = 0; it < 8; ++it) {
        float qv = qs[64 * w + 8 * it + lg];
        la.x += qv * xr[it].x; la.y += qv * xr[it].y;
        la.z += qv * xr[it].z; la.w += qv * xr[it].w;
    }
    #pragma unroll
    for (int st = 8; st <= 32; st <<= 1) {
        la.x += __shfl_xor(la.x, st); la.y += __shfl_xor(la.y, st);
        la.z += __shfl_xor(la.z, st); la.w += __shfl_xor(la.w, st);
    }
    if (w > 0 && l < 8) comb[w - 1][l] = la;
    __syncthreads();
    // Phase 2: wave 0 lanes 0..7 finish logits, chunk-local softmax over 32.
    if (w == 0 && l < 8) {
        #pragma unroll
        for (int i = 0; i < 7; ++i) {
            float4 t = comb[i][l];
            la.x += t.x; la.y += t.y; la.z += t.z; la.w += t.w;
        }
        const float scale = 0.04419417382415922f; // 512^-0.5
        la.x *= scale; la.y *= scale; la.z *= scale; la.w *= scale;
        float m = fmaxf(fmaxf(la.x, la.y), fmaxf(la.z, la.w));
        m = fmaxf(m, __shfl_xor(m, 1));
        m = fmaxf(m, __shfl_xor(m, 2));
        m = fmaxf(m, __shfl_xor(m, 4));
        float4 p;
        p.x = expf(la.x - m); p.y = expf(la.y - m);
        p.z = expf(la.z - m); p.w = expf(la.w - m);
        float s = p.x + p.y + p.z + p.w;
        s += __shfl_xor(s, 1); s += __shfl_xor(s, 2); s += __shfl_xor(s, 4);
        p4s[l] = p;
        if (l == 0) { stats[blockIdx.x * 2] = m; stats[blockIdx.x * 2 + 1] = s; }
    }
    __syncthreads();
    // Phase 3: pooled partials from REGISTERS. xor over lp bits (8 indep chains).
    float4 pw = p4s[lp];
    #pragma unroll
    for (int it = 0; it < 8; ++it) {
        float r = pw.x * xr[it].x + pw.y * xr[it].y + pw.z * xr[it].z + pw.w * xr[it].w;
        r += __shfl_xor(r, 1); r += __shfl_xor(r, 2); r += __shfl_xor(r, 4);
        if (lp == 0) partLDS[64 * w + 8 * it + lg] = r;
    }
    __syncthreads();
    if (tid < CC / 4)
        ((float4*)(part + (size_t)blockIdx.x * CC))[tid] = ((float4*)partLDS)[tid];
}

// ---- C: merged combine+gate (one 16-block kernel, pooled stays in LDS) ----
// pooled[c] = sum_ch wgt[ch]*part[ch][c], wgt[ch] = e^{M_ch-M}/D, then
// gate[b,o] = Wv[o,:]·pooled + bv[o] for this block's half of o.
__global__ __launch_bounds__(256) void k_cg(const float* __restrict__ part,
                                            const float* __restrict__ stats,
                                            const float* __restrict__ Wv,
                                            const float* __restrict__ bv,
                                            float* __restrict__ gate) {
    __shared__ float wgt[NCH];
    __shared__ __align__(16) float pooledLDS[CC];
    __shared__ float redm[4], reds[4];
    int b = blockIdx.x >> 1, half = blockIdx.x & 1;
    int tid = threadIdx.x;
    float m1 = stats[((size_t)b * NCH + tid) * 2];
    float s1 = stats[((size_t)b * NCH + tid) * 2 + 1];
    float m2 = stats[((size_t)b * NCH + tid + 256) * 2];
    float s2 = stats[((size_t)b * NCH + tid + 256) * 2 + 1];
    float m = fmaxf(m1, m2);
    #pragma unroll
    for (int off = 32; off; off >>= 1) m = fmaxf(m, __shfl_xor(m, off));
    if ((tid & 63) == 0) redm[tid >> 6] = m;
    __syncthreads();
    m = fmaxf(fmaxf(redm[0], redm[1]), fmaxf(redm[2], redm[3]));
    float w1 = expf(m1 - m), w2 = expf(m2 - m);
    float d = w1 * s1 + w2 * s2;
    #pragma unroll
    for (int off = 32; off; off >>= 1) d += __shfl_xor(d, off);
    if ((tid & 63) == 0) reds[tid >> 6] = d;
    __syncthreads();
    float inv = 1.f / (reds[0] + reds[1] + reds[2] + reds[3]);
    wgt[tid] = w1 * inv; wgt[tid + 256] = w2 * inv;
    __syncthreads();
    // pooled (full 512 channels per block; redundant x2 per batch, trivial)
    float acc0 = 0.f, acc1 = 0.f;
    #pragma unroll 8
    for (int ch = 0; ch < NCH; ++ch) {
        const float* pr = part + ((size_t)b * NCH + ch) * CC;
        float w = wgt[ch];
        acc0 += w * pr[tid];
        acc1 += w * pr[tid + 256];
    }
    pooledLDS[tid] = acc0; pooledLDS[tid + 256] = acc1;
    __syncthreads();
    int o = half * 256 + tid;
    const float4* wr = (const float4*)(Wv + (size_t)o * CC);
    const float4* pl = (const float4*)pooledLDS;   // wave-uniform idx -> broadcast
    float acc = 0.f;
    #pragma unroll 8
    for (int i = 0; i < CC / 4; ++i) {
        float4 w = wr[i], p = pl[i];
        acc += w.x * p.x + w.y * p.y + w.z * p.z + w.w * p.w;
    }
    gate[b * CC + o] = acc + bv[o];
}

// ---- D: out[b,c,hw] = x[b,c,hw] * gate[b,c]   (read+write: 536 MB) ----
// NT loads AND NT stores (clang ext_vector type — HIP float4 rejected by the
// builtins): x is read-for-the-last-time, out is write-once/never-read ->
// bypass cache allocation on both sides of the 536 MB stream.
__global__ __launch_bounds__(256) void k_out(const float* __restrict__ x,
                                             const float* __restrict__ gate,
                                             float* __restrict__ out) {
    int bc = blockIdx.x;                          // 0..4095
    float g = gate[bc];
    const f32x4* xr  = (const f32x4*)x + (size_t)bc * HW4;
    f32x4*       orow = (f32x4*)out    + (size_t)bc * HW4;
    #pragma unroll 8
    for (int i = threadIdx.x; i < HW4; i += 256) {
        f32x4 v = __builtin_nontemporal_load(xr + i);
        f32x4 o = { v.x * g, v.y * g, v.z * g, v.w * g };
        __builtin_nontemporal_store(o, orow + i);
    }
}

extern "C" void kernel_launch(void* const* d_in, const int* in_sizes, int n_in,
                              void* d_out, int out_size, void* d_ws, size_t ws_size,
                              hipStream_t stream) {
    const float* x   = (const float*)d_in[0];
    const float* ctx = (const float*)d_in[1];
    const float* Wq  = (const float*)d_in[2];
    const float* bq  = (const float*)d_in[3];
    const float* Wk  = (const float*)d_in[4];
    // d_in[5] = bk: per-batch constant in logits -> dropped (softmax shift-invariant)
    const float* Wv  = (const float*)d_in[6];
    const float* bv  = (const float*)d_in[7];
    float* out = (float*)d_out;

    // Workspace layout (floats): everything written before read, no zero-init.
    float* ws    = (float*)d_ws;
    float* qk    = ws;                  // 4096
    float* gate  = ws + 4096;           // 4096
    float* stats = ws + 8192;           // 8192  (4096 chunks x {M, s})
    float* part  = ws + 16384;          // 2 M floats (4096 chunks x 512 channels)

    k_qk2  <<<  16, 256, 0, stream>>>(ctx, Wq, bq, Wk, qk);
    k_fused<<<4096, 512, 0, stream>>>(x, qk, part, stats);
    k_cg   <<<  16, 256, 0, stream>>>(part, stats, Wv, bv, gate);
    k_out  <<<4096, 256, 0, stream>>>(x, gate, out);
}